// Round 4
// baseline (111307.678 us; speedup 1.0000x reference)
//
#include <hip/hip_runtime.h>
#include <hip/hip_cooperative_groups.h>

namespace cg = cooperative_groups;

#define LSEQ 700
#define NB   32
#define DIN  41
#define HID  800
#define G4   3200   // 4*H gate rows
#define H2   1600   // 2*H
#define DKP  64     // Din padded to MFMA K granularity

#define SCAL 2048.f
#define ISC  (1.f/2048.f)

typedef _Float16 h8v __attribute__((ext_vector_type(8)));  // 8 f16 = 4 VGPRs (MFMA A/B frag)
typedef float    f4v __attribute__((ext_vector_type(4)));

// All workspace pointers + params in one POD (single kernel arg; coop-launch friendly)
struct P {
  const float *x, *w_ih0, *w_hh0, *b_ih0, *b_hh0;
  const float *w_ih1, *w_hh1, *b_ih1, *b_hh1;
  const float *w_lin, *b_lin, *alphabet;
  _Float16 *h0;                    // [t][b][dir*800+u] f16 hi — full history (layer1 GEMM input)
  _Float16 *hr0h, *hr0l;           // layer0 prev-h ring [2][b][dir*800+u], lo scaled by 2048
  _Float16 *h1wh, *h1wl;           // layer1 ring [SL=Tc+1][b][dir*800+u], lo scaled by 2048
  _Float16 *w0hh, *w1hh;           // [dir][permrow 4u+g][800]
  _Float16 *w1ih;                  // [dir][permrow][1600]
  _Float16 *w0ih;                  // [dir][permrow][64] (Din padded)
  _Float16 *xp;                    // [t][b][64]
  float *bias0, *bias1;            // [dir][permrow] = b_ih+b_hh
  float *logits0, *logits1;        // [t][b][20] per-dir partial logits (write-once)
  float *dvec;                     // [3L][j][4]: d0,d1,d2 (NeRF-scan order!)
  float *gx1;                      // [d][sl][row/4][b][4] f32
  float *out;
  int Tc, nchunks;
};

__device__ __forceinline__ h8v ldv(const _Float16* p_){ return *(const h8v*)p_; }

// ---- prep: permuted-row f16 weights. newrow = 4*u + gate (gate order i,f,g,o)
// so one MFMA C-fragment lane (row=quad*4+r) holds all 4 gates of one unit.
__global__ void prep_w(const float* __restrict__ src, _Float16* __restrict__ dst,
                       int Ks, int Kd){
  const long n = (long)2*G4*Kd;
  for (long i = blockIdx.x*(long)blockDim.x + threadIdx.x; i < n; i += (long)gridDim.x*blockDim.x){
    const int k  = (int)(i % Kd);
    const long rr = i / Kd;
    const int nr = (int)(rr % G4);
    const int d  = (int)(rr / G4);
    float v = 0.f;
    if (k < Ks){
      const int u = nr >> 2, g = nr & 3;
      v = src[((long)d*G4 + g*HID + u)*Ks + k];
    }
    dst[i] = (_Float16)v;
  }
}

__global__ void prep_xpad(const float* __restrict__ x, _Float16* __restrict__ dst){
  const long n = (long)LSEQ*NB*DKP;
  for (long i = blockIdx.x*(long)blockDim.x + threadIdx.x; i < n; i += (long)gridDim.x*blockDim.x){
    const int k = (int)(i % DKP);
    const long rr = i / DKP;
    const int bb = (int)(rr % NB);
    const int t  = (int)(rr / NB);
    float v = 0.f;
    if (k < DIN) v = x[((long)bb*LSEQ + t)*DIN + k];   // x is [B][L][Din]
    dst[i] = (_Float16)v;
  }
}

__global__ void prep_bias(const float* bi0, const float* bh0, const float* bi1, const float* bh1,
                          float* o0, float* o1){
  for (int i = blockIdx.x*blockDim.x + threadIdx.x; i < 2*G4; i += gridDim.x*blockDim.x){
    const int nr = i % G4, d = i / G4;
    const int u = nr >> 2, g = nr & 3;
    const int old = d*G4 + g*HID + u;
    o0[i] = bi0[old] + bh0[old];
    o1[i] = bi1[old] + bh1[old];
  }
}

// ---- layer 0: fused x-projection + recurrence. grid 256 (128/dir), 100 active WGs/dir.
// wave (Mtile m, Ntile nt): 16 gate-rows (=4 units) x 16 batches. c-state in 1 VGPR/lane.
// Recurrent h read from hr0 ring in split f16 (hi + lo*2048) for ~fp32 feedback precision.
__global__ void __launch_bounds__(256, 1) layer0_kernel(P p){
  cg::grid_group grid = cg::this_grid();
  const int wg  = blockIdx.x;
  const int dir = wg >> 7;
  const int wgd = wg & 127;
  const int wid = threadIdx.x >> 6;
  const int lane = threadIdx.x & 63;
  const int q = lane >> 4, c16 = lane & 15;
  const bool act = (wgd < 100);
  const int wv = wgd*4 + wid;
  const int m  = wv >> 1;          // Mtile 0..199
  const int nt = wv & 1;
  const int b  = nt*16 + c16;
  const int ulocal = (wid >> 1)*4 + q;   // 0..7; WG owns units 8*wgd..8*wgd+7
  const int rowb = m*16 + q*4;
  float cst = 0.f;
  __shared__ _Float16 hT[2][8][32];

  const long wih_row = ((long)dir*G4 + m*16 + c16)*DKP;
  const long whh_row = ((long)dir*G4 + m*16 + c16)*HID;
  f4v bias = {0.f,0.f,0.f,0.f};
  if (act) bias = *(const f4v*)(p.bias0 + dir*G4 + rowb);

  for (int s = 0; s < LSEQ; ++s){
    const int t  = dir ? (LSEQ-1-s) : s;
    if (act){
      f4v acc = {0.f,0.f,0.f,0.f};
      f4v accl = {0.f,0.f,0.f,0.f};
      const long xb = ((long)t*NB + b)*DKP;
      #pragma unroll
      for (int kk = 0; kk < 2; ++kk){
        const int ko = kk*32 + q*8;
        acc = __builtin_amdgcn_mfma_f32_16x16x32_f16(
                ldv(p.w0ih + wih_row + ko), ldv(p.xp + xb + ko), acc, 0, 0, 0);
      }
      if (s > 0){
        const long hb = ((long)((s-1)&1)*NB + b)*H2 + dir*HID;
        #pragma unroll
        for (int kk = 0; kk < 25; ++kk){
          const int ko = kk*32 + q*8;
          const h8v aw = ldv(p.w0hh + whh_row + ko);
          acc  = __builtin_amdgcn_mfma_f32_16x16x32_f16(aw, ldv(p.hr0h + hb + ko), acc,  0, 0, 0);
          accl = __builtin_amdgcn_mfma_f32_16x16x32_f16(aw, ldv(p.hr0l + hb + ko), accl, 0, 0, 0);
        }
      }
      const float gi = acc[0] + accl[0]*ISC + bias[0];
      const float gf = acc[1] + accl[1]*ISC + bias[1];
      const float gg = acc[2] + accl[2]*ISC + bias[2];
      const float go = acc[3] + accl[3]*ISC + bias[3];
      const float si = 1.f/(1.f + __expf(-gi));
      const float sf = 1.f/(1.f + __expf(-gf));
      const float so = 1.f/(1.f + __expf(-go));
      cst = sf*cst + si*tanhf(gg);
      const float h = so*tanhf(cst);
      const _Float16 hi = (_Float16)h;
      hT[0][ulocal][b] = hi;
      hT[1][ulocal][b] = (_Float16)((h - (float)hi)*SCAL);
    }
    __syncthreads();
    if (act && threadIdx.x < 64){   // transpose-out: contiguous 16B per batch row
      const int part = threadIdx.x >> 5, bb = threadIdx.x & 31;
      h8v v;
      #pragma unroll
      for (int uu = 0; uu < 8; ++uu) v[uu] = hT[part][uu][bb];
      const long fo = (long)bb*H2 + dir*HID + wgd*8;
      if (part == 0){
        *(h8v*)(p.h0   + (long)t*NB*H2 + fo) = v;
        *(h8v*)(p.hr0h + (long)(s&1)*NB*H2 + fo) = v;
      } else {
        *(h8v*)(p.hr0l + (long)(s&1)*NB*H2 + fo) = v;
      }
    }
    __threadfence();
    grid.sync();
    __threadfence();
  }
}

// ---- layer 1: per chunk: GEMM (gx1 = Wih1.h0 + bias) -> Tc recurrent steps (split ring)
// -> per-chunk logits projection (so h1 never fully materialized).
__global__ void __launch_bounds__(256, 1) layer1_kernel(P p){
  cg::grid_group grid = cg::this_grid();
  const int wg  = blockIdx.x;
  const int dir = wg >> 7;
  const int wgd = wg & 127;
  const int wid = threadIdx.x >> 6;
  const int lane = threadIdx.x & 63;
  const int q = lane >> 4, c16 = lane & 15;
  const bool act = (wgd < 100);
  const int wv = wgd*4 + wid;
  const int m  = wv >> 1;
  const int nt = wv & 1;
  const int b  = nt*16 + c16;
  const int ulocal = (wid >> 1)*4 + q;
  const int rowb = m*16 + q*4;
  float cst = 0.f;
  __shared__ _Float16 hT[2][8][32];
  const long whh_row = ((long)dir*G4 + m*16 + c16)*HID;
  const int Tc = p.Tc;
  const int SL = Tc + 1;
  const int ntN = Tc >> 2;             // 128-wide N tiles per dir
  const int tilesPerDir = 25*ntN;
  const int TILES = 2*tilesPerDir;

  for (int ci = 0; ci < p.nchunks; ++ci){
    // ---------- GEMM phase: per-WG 128x128 tile; per-wave 64x64 ----------
    for (int tile = blockIdx.x; tile < TILES; tile += gridDim.x){
      const int d   = tile / tilesPerDir;
      const int rem = tile % tilesPerDir;
      const int mi  = rem / ntN;
      const int ni  = rem % ntN;
      const int M0  = mi*128 + (wid >> 1)*64;
      const int N0  = ni*128 + (wid & 1)*64;
      f4v acc[4][4];
      const f4v zz = {0.f,0.f,0.f,0.f};
      #pragma unroll
      for (int ai=0; ai<4; ++ai)
        #pragma unroll
        for (int bi=0; bi<4; ++bi) acc[ai][bi] = zz;
      long hrow[4], arow[4];
      #pragma unroll
      for (int bi=0; bi<4; ++bi){
        const int n0 = N0 + bi*16;
        const int j  = n0 >> 5;
        const int bb = (n0 & 31) + c16;
        const int t  = d ? (LSEQ-1 - (ci*Tc + j)) : (ci*Tc + j);
        hrow[bi] = ((long)t*NB + bb)*H2;
      }
      #pragma unroll
      for (int ai=0; ai<4; ++ai) arow[ai] = ((long)d*G4 + M0 + ai*16 + c16)*H2;

      for (int kk = 0; kk < 50; ++kk){
        const int ko = kk*32 + q*8;
        h8v Ah[4], Bh[4];
        #pragma unroll
        for (int ai=0; ai<4; ++ai) Ah[ai] = ldv(p.w1ih + arow[ai] + ko);
        #pragma unroll
        for (int bi=0; bi<4; ++bi) Bh[bi] = ldv(p.h0 + hrow[bi] + ko);
        #pragma unroll
        for (int ai=0; ai<4; ++ai)
          #pragma unroll
          for (int bi=0; bi<4; ++bi)
            acc[ai][bi] = __builtin_amdgcn_mfma_f32_16x16x32_f16(Ah[ai], Bh[bi], acc[ai][bi], 0, 0, 0);
      }
      #pragma unroll
      for (int ai=0; ai<4; ++ai){
        const int row0 = M0 + ai*16 + q*4;
        const f4v bv = *(const f4v*)(p.bias1 + d*G4 + row0);
        #pragma unroll
        for (int bi=0; bi<4; ++bi){
          const int n0 = N0 + bi*16;
          const int j  = n0 >> 5;
          const int bb = (n0 & 31) + c16;
          f4v val = acc[ai][bi] + bv;
          // gx1 layout: [d][sl][row/4][b][4]
          *(f4v*)(p.gx1 + ((((long)d*Tc + j)*800 + (row0 >> 2))*NB + bb)*4) = val;
        }
      }
    }
    __threadfence();
    grid.sync();
    __threadfence();
    // ---------- recurrent steps ----------
    for (int sl = 0; sl < Tc; ++sl){
      const int s  = ci*Tc + sl;
      if (act){
        f4v acc = *(const f4v*)(p.gx1 + ((((long)dir*Tc + sl)*800 + (rowb >> 2))*NB + b)*4);
        f4v accl = {0.f,0.f,0.f,0.f};
        if (s > 0){
          const int slotp = (s-1) % SL;
          const long hb = ((long)slotp*NB + b)*H2 + dir*HID;
          #pragma unroll
          for (int kk = 0; kk < 25; ++kk){
            const int ko = kk*32 + q*8;
            const h8v aw = ldv(p.w1hh + whh_row + ko);
            acc  = __builtin_amdgcn_mfma_f32_16x16x32_f16(aw, ldv(p.h1wh + hb + ko), acc,  0, 0, 0);
            accl = __builtin_amdgcn_mfma_f32_16x16x32_f16(aw, ldv(p.h1wl + hb + ko), accl, 0, 0, 0);
          }
        }
        const float si = 1.f/(1.f + __expf(-(acc[0] + accl[0]*ISC)));
        const float sf = 1.f/(1.f + __expf(-(acc[1] + accl[1]*ISC)));
        const float so = 1.f/(1.f + __expf(-(acc[3] + accl[3]*ISC)));
        cst = sf*cst + si*tanhf(acc[2] + accl[2]*ISC);
        const float h = so*tanhf(cst);
        const _Float16 hi = (_Float16)h;
        hT[0][ulocal][b] = hi;
        hT[1][ulocal][b] = (_Float16)((h - (float)hi)*SCAL);
      }
      __syncthreads();
      if (act && threadIdx.x < 64){
        const int part = threadIdx.x >> 5, bb2 = threadIdx.x & 31;
        const int slot = (ci*Tc + sl) % SL;
        h8v v;
        #pragma unroll
        for (int uu = 0; uu < 8; ++uu) v[uu] = hT[part][uu][bb2];
        _Float16* dst = (part ? p.h1wl : p.h1wh) + ((long)slot*NB + bb2)*H2 + dir*HID + wgd*8;
        *(h8v*)dst = v;
      }
      __threadfence();
      grid.sync();
      __threadfence();
    }
    // ---------- logits phase: logits_d[t][b][k] = W_lin[k, d*800:] . h1_d[t] ----------
    for (int pi = blockIdx.x; pi < 2*Tc; pi += gridDim.x){
      const int sl = pi >> 1, d = pi & 1;
      const int s  = ci*Tc + sl;
      const int t  = d ? (LSEQ-1-s) : s;
      const int slot = s % SL;
      const int bb = threadIdx.x & 31;
      const int k0 = threadIdx.x >> 5;     // 0..7
      const _Float16* hp = p.h1wh + ((long)slot*NB + bb)*H2 + d*HID;
      const _Float16* lp2 = p.h1wl + ((long)slot*NB + bb)*H2 + d*HID;
      float* lp = (d ? p.logits1 : p.logits0) + ((long)t*NB + bb)*20;
      for (int k = k0; k < 20; k += 8){
        const float* wrow = p.w_lin + (long)k*H2 + d*HID;
        float acc2 = 0.f;
        for (int u = 0; u < HID; u += 8){
          h8v hv = ldv(hp + u);
          h8v lv = ldv(lp2 + u);
          #pragma unroll
          for (int j2 = 0; j2 < 8; ++j2)
            acc2 += ((float)hv[j2] + (float)lv[j2]*ISC) * wrow[u + j2];
        }
        lp[k] = acc2;
      }
    }
    __threadfence();
    grid.sync();
    __threadfence();
  }
}

// ---- head: logits -> softmax over BATCH axis (dim=1, faithful) -> angles -> dvec.
// CRITICAL: reference does phis = ang.reshape(3L, B) on row-major [L,B,3]:
//   phis[3l+p][j] = ang[l][(32p+j)/3][(32p+j)%3], while r/theta = BL[p]/BA[p].
__global__ void head_kernel(P p){
  const int l = blockIdx.x;
  const int tid = threadIdx.x;
  __shared__ float lg[NB][20];
  __shared__ float sA[20][3], cA2[20][3];
  if (tid < 60){
    const float a = p.alphabet[tid];
    sA[tid/3][tid%3]  = sinf(a);
    cA2[tid/3][tid%3] = cosf(a);
  }
  for (int i = tid; i < NB*20; i += blockDim.x){
    const int bb = i / 20, k = i % 20;
    lg[bb][k] = p.logits0[((long)l*NB + bb)*20 + k] +
                p.logits1[((long)l*NB + bb)*20 + k] + p.b_lin[k];
  }
  __syncthreads();
  if (tid < 20){
    float mx = -1e30f;
    for (int bb=0; bb<NB; ++bb) mx = fmaxf(mx, lg[bb][tid]);
    float sum = 0.f;
    for (int bb=0; bb<NB; ++bb) sum += expf(lg[bb][tid] - mx);
    const float inv = 1.f/sum;
    for (int bb=0; bb<NB; ++bb) lg[bb][tid] = expf(lg[bb][tid] - mx)*inv;
  }
  __syncthreads();
  if (tid < 96){
    const int bb = tid/3, dd = tid%3;     // ang indices (angle source)
    const int pp = tid >> 5;              // scan row within the step-triple
    const int j  = tid & 31;              // NeRF batch-lane (column of phis)
    float ss = 0.f, cc = 0.f;
    #pragma unroll
    for (int k=0; k<20; ++k){ ss += lg[bb][k]*sA[k][dd]; cc += lg[bb][k]*cA2[k][dd]; }
    const float phi = atan2f(ss, cc);
    const float BL[3] = {145.801f, 152.326f, 132.868f};
    const float BA[3] = {2.124f, 1.941f, 2.028f};
    const float r = BL[pp], th = BA[pp];
    float* dv = p.dvec + ((long)(l*3 + pp)*NB + j)*4;
    dv[0] = -r*cosf(th);
    dv[1] = r*sinf(th)*cosf(phi);
    dv[2] = r*sinf(th)*sinf(phi);
  }
}

// ---- NeRF extension: strictly sequential, 1 lane per scan column.
__global__ void nerf_kernel(P p){
  const int bb = threadIdx.x;
  if (bb >= NB) return;
  float ax=0.f,ay=0.f,az=0.f, bx=100.f,by=0.f,bz=0.f, cx=200.f,cy=100.f,cz=0.f;
  for (int i = 0; i < 3*LSEQ; ++i){
    const float* dv = p.dvec + ((long)i*NB + bb)*4;
    const float d0=dv[0], d1=dv[1], d2=dv[2];
    float ux=cx-bx, uy=cy-by, uz=cz-bz;
    float inv = 1.f/(sqrtf(ux*ux+uy*uy+uz*uz)+1e-12f);
    ux*=inv; uy*=inv; uz*=inv;                     // bc
    const float px=bx-ax, py=by-ay, pz=bz-az;      // b-a
    float nx=py*uz-pz*uy, ny=pz*ux-px*uz, nz=px*uy-py*ux;
    inv = 1.f/(sqrtf(nx*nx+ny*ny+nz*nz)+1e-12f);
    nx*=inv; ny*=inv; nz*=inv;                     // n
    const float mx=ny*uz-nz*uy, my=nz*ux-nx*uz, mz=nx*uy-ny*ux;  // m2 = cross(n,bc)
    const float Dx = cx + d0*ux + d1*mx + d2*nx;
    const float Dy = cy + d0*uy + d1*my + d2*ny;
    const float Dz = cz + d0*uz + d1*mz + d2*nz;
    float* o = p.out + ((long)i*NB + bb)*3;
    o[0]=Dx; o[1]=Dy; o[2]=Dz;
    ax=bx; ay=by; az=bz;
    bx=cx; by=cy; bz=cz;
    cx=Dx; cy=Dy; cz=Dz;
  }
}

extern "C" void kernel_launch(void* const* d_in, const int* in_sizes, int n_in,
                              void* d_out, int out_size, void* d_ws, size_t ws_size,
                              hipStream_t stream){
  P p{};
  p.x      = (const float*)d_in[0];
  p.w_ih0  = (const float*)d_in[1];
  p.w_hh0  = (const float*)d_in[2];
  p.b_ih0  = (const float*)d_in[3];
  p.b_hh0  = (const float*)d_in[4];
  p.w_ih1  = (const float*)d_in[5];
  p.w_hh1  = (const float*)d_in[6];
  p.b_ih1  = (const float*)d_in[7];
  p.b_hh1  = (const float*)d_in[8];
  p.w_lin  = (const float*)d_in[9];
  p.b_lin  = (const float*)d_in[10];
  p.alphabet = (const float*)d_in[11];
  p.out    = (float*)d_out;

  char* base = (char*)d_ws;
  size_t off = 0;
  auto alloc = [&](size_t bytes)->void*{
    void* r = base + off;
    off = (off + bytes + 255) & ~(size_t)255;
    return r;
  };
  p.h0      = (_Float16*)alloc((size_t)LSEQ*NB*H2*2);       // 71.68 MB
  p.hr0h    = (_Float16*)alloc((size_t)2*NB*H2*2);          //  0.20 MB
  p.hr0l    = (_Float16*)alloc((size_t)2*NB*H2*2);          //  0.20 MB
  p.w0hh    = (_Float16*)alloc((size_t)2*G4*HID*2);         // 10.24 MB
  p.w1hh    = (_Float16*)alloc((size_t)2*G4*HID*2);         // 10.24 MB
  p.w1ih    = (_Float16*)alloc((size_t)2*G4*H2*2);          // 20.48 MB
  p.w0ih    = (_Float16*)alloc((size_t)2*G4*DKP*2);         //  0.82 MB
  p.xp      = (_Float16*)alloc((size_t)LSEQ*NB*DKP*2);      //  2.87 MB
  p.bias0   = (float*)alloc((size_t)2*G4*4);
  p.bias1   = (float*)alloc((size_t)2*G4*4);
  p.logits0 = (float*)alloc((size_t)LSEQ*NB*20*4);          //  1.79 MB
  p.logits1 = (float*)alloc((size_t)LSEQ*NB*20*4);          //  1.79 MB
  p.dvec    = (float*)alloc((size_t)3*LSEQ*NB*4*4);         //  1.08 MB

  // Tc: largest divisor of 700 (mult of 4) whose gx1 + split h1 ring fit remaining ws
  const int cands[4] = {140, 28, 20, 4};
  int Tc = 4;
  for (int i = 0; i < 4; ++i){
    const size_t need = off
      + (size_t)2*cands[i]*800*NB*4*4 + 256          // gx1
      + (size_t)2*(cands[i]+1)*NB*H2*2 + 512;        // h1wh + h1wl rings
    if (need <= ws_size){ Tc = cands[i]; break; }
  }
  p.gx1  = (float*)alloc((size_t)2*Tc*800*NB*4*4);
  p.h1wh = (_Float16*)alloc((size_t)(Tc+1)*NB*H2*2);
  p.h1wl = (_Float16*)alloc((size_t)(Tc+1)*NB*H2*2);
  p.Tc = Tc;
  p.nchunks = LSEQ / Tc;

  hipLaunchKernelGGL(prep_w, dim3(1024), dim3(256), 0, stream, p.w_hh0, p.w0hh, HID, HID);
  hipLaunchKernelGGL(prep_w, dim3(1024), dim3(256), 0, stream, p.w_hh1, p.w1hh, HID, HID);
  hipLaunchKernelGGL(prep_w, dim3(2048), dim3(256), 0, stream, p.w_ih1, p.w1ih, H2, H2);
  hipLaunchKernelGGL(prep_w, dim3(256),  dim3(256), 0, stream, p.w_ih0, p.w0ih, DIN, DKP);
  hipLaunchKernelGGL(prep_xpad, dim3(512), dim3(256), 0, stream, p.x, p.xp);
  hipLaunchKernelGGL(prep_bias, dim3(32), dim3(256), 0, stream,
                     p.b_ih0, p.b_hh0, p.b_ih1, p.b_hh1, p.bias0, p.bias1);

  void* args[] = { &p };
  hipLaunchCooperativeKernel((void*)layer0_kernel, dim3(256), dim3(256), args, 0, stream);
  hipLaunchCooperativeKernel((void*)layer1_kernel, dim3(256), dim3(256), args, 0, stream);
  hipLaunchKernelGGL(head_kernel, dim3(LSEQ), dim3(256), 0, stream, p);
  hipLaunchKernelGGL(nerf_kernel, dim3(1), dim3(64), 0, stream, p);
}

// Round 7
// 35501.505 us; speedup vs baseline: 3.1353x; 3.1353x over previous
//
#include <hip/hip_runtime.h>

#define LSEQ 700
#define NB   32
#define DIN  41
#define HID  800
#define G4   3200   // 4*H gate rows
#define H2   1600   // 2*H
#define DKP  64     // Din padded to MFMA K granularity

#define SCAL 2048.f
#define ISC  (1.f/2048.f)

// barrier region: 256 arrive flags (64B stride) + 64 replicated go words (64B stride)
#define GOOFF (256*16)
#define BARN  (256*16 + 64*16)

typedef _Float16 h8v __attribute__((ext_vector_type(8)));  // 8 f16 = 4 VGPRs (MFMA A/B frag)
typedef float    f4v __attribute__((ext_vector_type(4)));

struct P {
  const float *x, *w_ih0, *w_hh0, *b_ih0, *b_hh0;
  const float *w_ih1, *w_hh1, *b_ih1, *b_hh1;
  const float *w_lin, *b_lin, *alphabet;
  _Float16 *h0;                    // [t][b][dir*800+u] f16 hi — full history (layer1 GEMM input)
  _Float16 *hr0h, *hr0l;           // layer0 prev-h ring [2][b][dir*800+u], lo scaled by 2048
  _Float16 *h1wh, *h1wl;           // layer1 ring [SL=Tc+1][b][dir*800+u], lo scaled by 2048
  _Float16 *w0hh, *w1hh;           // [dir][permrow 4u+g][800]
  _Float16 *w1ih;                  // [dir][permrow][1600]
  _Float16 *w0ih;                  // [dir][permrow][64]
  _Float16 *xp;                    // [t][b][64]
  float *bias0, *bias1;            // [dir][permrow]
  float *logits0, *logits1;        // [t][b][20]
  float *dvec;                     // [3L][j][4]
  float *gx1;                      // [d][sl][unit][b][4] f32
  float *out;
  int *bar0, *bar1;
  int Tc, nchunks;
};

__device__ __forceinline__ h8v ldv(const _Float16* p_){ return *(const h8v*)p_; }

// BISECT R7: verbatim R4 compute; ONLY the barrier is replaced by this
// contention-free distributed barrier with canonical release/acquire fences.
__device__ __forceinline__ void gbar(int* bar, int ep){
  __syncthreads();                       // all waves drain vmcnt -> stores complete to L2
  if (threadIdx.x == 0){
    __builtin_amdgcn_fence(__ATOMIC_RELEASE, "agent");   // L2 writeback to coherence point
    __hip_atomic_store(&bar[blockIdx.x*16], ep, __ATOMIC_RELAXED, __HIP_MEMORY_SCOPE_AGENT);
  }
  if (blockIdx.x == 0){
    for (int i = threadIdx.x; i < (int)gridDim.x; i += blockDim.x)
      while (__hip_atomic_load(&bar[i*16], __ATOMIC_RELAXED, __HIP_MEMORY_SCOPE_AGENT) < ep)
        __builtin_amdgcn_s_sleep(1);
    __syncthreads();
    if (threadIdx.x < 64)
      __hip_atomic_store(&bar[GOOFF + threadIdx.x*16], ep, __ATOMIC_RELAXED, __HIP_MEMORY_SCOPE_AGENT);
  } else {
    if (threadIdx.x == 0){
      while (__hip_atomic_load(&bar[GOOFF + (blockIdx.x & 63)*16], __ATOMIC_RELAXED, __HIP_MEMORY_SCOPE_AGENT) < ep)
        __builtin_amdgcn_s_sleep(1);
    }
  }
  __syncthreads();
  __builtin_amdgcn_fence(__ATOMIC_ACQUIRE, "agent");     // invalidate caches: fresh loads
}

// ---- prep: permuted-row f16 weights. newrow = 4*u + gate (gate order i,f,g,o)
__global__ void prep_w(const float* __restrict__ src, _Float16* __restrict__ dst,
                       int Ks, int Kd){
  const long n = (long)2*G4*Kd;
  for (long i = blockIdx.x*(long)blockDim.x + threadIdx.x; i < n; i += (long)gridDim.x*blockDim.x){
    const int k  = (int)(i % Kd);
    const long rr = i / Kd;
    const int nr = (int)(rr % G4);
    const int d  = (int)(rr / G4);
    float v = 0.f;
    if (k < Ks){
      const int u = nr >> 2, g = nr & 3;
      v = src[((long)d*G4 + g*HID + u)*Ks + k];
    }
    dst[i] = (_Float16)v;
  }
}

__global__ void prep_xpad(const float* __restrict__ x, _Float16* __restrict__ dst){
  const long n = (long)LSEQ*NB*DKP;
  for (long i = blockIdx.x*(long)blockDim.x + threadIdx.x; i < n; i += (long)gridDim.x*blockDim.x){
    const int k = (int)(i % DKP);
    const long rr = i / DKP;
    const int bb = (int)(rr % NB);
    const int t  = (int)(rr / NB);
    float v = 0.f;
    if (k < DIN) v = x[((long)bb*LSEQ + t)*DIN + k];   // x is [B][L][Din]
    dst[i] = (_Float16)v;
  }
}

__global__ void prep_bias(const float* bi0, const float* bh0, const float* bi1, const float* bh1,
                          float* o0, float* o1, int* bar0, int* bar1){
  const int tid = blockIdx.x*blockDim.x + threadIdx.x;
  for (int i = tid; i < 2*G4; i += gridDim.x*blockDim.x){
    const int nr = i % G4, d = i / G4;
    const int u = nr >> 2, g = nr & 3;
    const int old = d*G4 + g*HID + u;
    o0[i] = bi0[old] + bh0[old];
    o1[i] = bi1[old] + bh1[old];
  }
  for (int i = tid; i < BARN; i += gridDim.x*blockDim.x){
    bar0[i] = 0;
    bar1[i] = 0;
  }
}

// ---- layer 0: VERBATIM R4 (grid 256, 128/dir, 100 active WGs/dir, 16-row waves).
__global__ void __launch_bounds__(256, 1) layer0_kernel(P p){
  const int wg  = blockIdx.x;
  const int dir = wg >> 7;
  const int wgd = wg & 127;
  const int wid = threadIdx.x >> 6;
  const int lane = threadIdx.x & 63;
  const int q = lane >> 4, c16 = lane & 15;
  const bool act = (wgd < 100);
  const int wv = wgd*4 + wid;
  const int m  = wv >> 1;          // Mtile 0..199
  const int nt = wv & 1;
  const int b  = nt*16 + c16;
  const int ulocal = (wid >> 1)*4 + q;   // 0..7; WG owns units 8*wgd..8*wgd+7
  const int rowb = m*16 + q*4;
  float cst = 0.f;
  __shared__ _Float16 hT[2][8][32];

  const long wih_row = ((long)dir*G4 + m*16 + c16)*DKP;
  const long whh_row = ((long)dir*G4 + m*16 + c16)*HID;
  f4v bias = {0.f,0.f,0.f,0.f};
  if (act) bias = *(const f4v*)(p.bias0 + dir*G4 + rowb);

  for (int s = 0; s < LSEQ; ++s){
    const int t  = dir ? (LSEQ-1-s) : s;
    if (act){
      f4v acc = {0.f,0.f,0.f,0.f};
      f4v accl = {0.f,0.f,0.f,0.f};
      const long xb = ((long)t*NB + b)*DKP;
      #pragma unroll
      for (int kk = 0; kk < 2; ++kk){
        const int ko = kk*32 + q*8;
        acc = __builtin_amdgcn_mfma_f32_16x16x32_f16(
                ldv(p.w0ih + wih_row + ko), ldv(p.xp + xb + ko), acc, 0, 0, 0);
      }
      if (s > 0){
        const long hb = ((long)((s-1)&1)*NB + b)*H2 + dir*HID;
        #pragma unroll
        for (int kk = 0; kk < 25; ++kk){
          const int ko = kk*32 + q*8;
          const h8v aw = ldv(p.w0hh + whh_row + ko);
          acc  = __builtin_amdgcn_mfma_f32_16x16x32_f16(aw, ldv(p.hr0h + hb + ko), acc,  0, 0, 0);
          accl = __builtin_amdgcn_mfma_f32_16x16x32_f16(aw, ldv(p.hr0l + hb + ko), accl, 0, 0, 0);
        }
      }
      const float gi = acc[0] + accl[0]*ISC + bias[0];
      const float gf = acc[1] + accl[1]*ISC + bias[1];
      const float gg = acc[2] + accl[2]*ISC + bias[2];
      const float go = acc[3] + accl[3]*ISC + bias[3];
      const float si = 1.f/(1.f + __expf(-gi));
      const float sf = 1.f/(1.f + __expf(-gf));
      const float so = 1.f/(1.f + __expf(-go));
      cst = sf*cst + si*tanhf(gg);
      const float h = so*tanhf(cst);
      const _Float16 hi = (_Float16)h;
      hT[0][ulocal][b] = hi;
      hT[1][ulocal][b] = (_Float16)((h - (float)hi)*SCAL);
    }
    __syncthreads();
    if (act && threadIdx.x < 64){   // transpose-out: contiguous 16B per batch row
      const int part = threadIdx.x >> 5, bb = threadIdx.x & 31;
      h8v v;
      #pragma unroll
      for (int uu = 0; uu < 8; ++uu) v[uu] = hT[part][uu][bb];
      const long fo = (long)bb*H2 + dir*HID + wgd*8;
      if (part == 0){
        *(h8v*)(p.h0   + (long)t*NB*H2 + fo) = v;
        *(h8v*)(p.hr0h + (long)(s&1)*NB*H2 + fo) = v;
      } else {
        *(h8v*)(p.hr0l + (long)(s&1)*NB*H2 + fo) = v;
      }
    }
    gbar(p.bar0, s+1);
  }
}

// ---- layer 1: VERBATIM R4 (grid 256, 100 active WGs/dir).
__global__ void __launch_bounds__(256, 1) layer1_kernel(P p){
  const int wg  = blockIdx.x;
  const int dir = wg >> 7;
  const int wgd = wg & 127;
  const int wid = threadIdx.x >> 6;
  const int lane = threadIdx.x & 63;
  const int q = lane >> 4, c16 = lane & 15;
  const bool act = (wgd < 100);
  const int wv = wgd*4 + wid;
  const int m  = wv >> 1;
  const int nt = wv & 1;
  const int b  = nt*16 + c16;
  const int ulocal = (wid >> 1)*4 + q;
  const int rowb = m*16 + q*4;
  float cst = 0.f;
  __shared__ _Float16 hT[2][8][32];
  const long whh_row = ((long)dir*G4 + m*16 + c16)*HID;
  const int Tc = p.Tc;
  const int SL = Tc + 1;
  const int ntN = Tc >> 2;
  const int tilesPerDir = 25*ntN;
  const int TILES = 2*tilesPerDir;
  int ep = 0;

  for (int ci = 0; ci < p.nchunks; ++ci){
    // ---------- GEMM phase ----------
    for (int tile = blockIdx.x; tile < TILES; tile += gridDim.x){
      const int d   = tile / tilesPerDir;
      const int rem = tile % tilesPerDir;
      const int mi  = rem / ntN;
      const int ni  = rem % ntN;
      const int M0  = mi*128 + (wid >> 1)*64;
      const int N0  = ni*128 + (wid & 1)*64;
      f4v acc[4][4];
      #pragma unroll
      for (int ai=0; ai<4; ++ai)
        #pragma unroll
        for (int bi=0; bi<4; ++bi) acc[ai][bi] = (f4v){0,0,0,0};
      long hrow[4], arow[4];
      #pragma unroll
      for (int bi=0; bi<4; ++bi){
        const int n0 = N0 + bi*16;
        const int j  = n0 >> 5;
        const int bb = (n0 & 31) + c16;
        const int t  = d ? (LSEQ-1 - (ci*Tc + j)) : (ci*Tc + j);
        hrow[bi] = ((long)t*NB + bb)*H2;
      }
      #pragma unroll
      for (int ai=0; ai<4; ++ai) arow[ai] = ((long)d*G4 + M0 + ai*16 + c16)*H2;

      for (int kk = 0; kk < 50; ++kk){
        const int ko = kk*32 + q*8;
        h8v Ah[4], Bh[4];
        #pragma unroll
        for (int ai=0; ai<4; ++ai) Ah[ai] = ldv(p.w1ih + arow[ai] + ko);
        #pragma unroll
        for (int bi=0; bi<4; ++bi) Bh[bi] = ldv(p.h0 + hrow[bi] + ko);
        #pragma unroll
        for (int ai=0; ai<4; ++ai)
          #pragma unroll
          for (int bi=0; bi<4; ++bi)
            acc[ai][bi] = __builtin_amdgcn_mfma_f32_16x16x32_f16(Ah[ai], Bh[bi], acc[ai][bi], 0, 0, 0);
      }
      #pragma unroll
      for (int ai=0; ai<4; ++ai){
        const int row0 = M0 + ai*16 + q*4;
        const f4v bv = *(const f4v*)(p.bias1 + d*G4 + row0);
        #pragma unroll
        for (int bi=0; bi<4; ++bi){
          const int n0 = N0 + bi*16;
          const int j  = n0 >> 5;
          const int bb = (n0 & 31) + c16;
          f4v val = acc[ai][bi] + bv;
          *(f4v*)(p.gx1 + ((((long)d*Tc + j)*800 + (row0 >> 2))*NB + bb)*4) = val;
        }
      }
    }
    gbar(p.bar1, ++ep);
    // ---------- recurrent steps ----------
    for (int sl = 0; sl < Tc; ++sl){
      const int s  = ci*Tc + sl;
      if (act){
        f4v acc = *(const f4v*)(p.gx1 + ((((long)dir*Tc + sl)*800 + (rowb >> 2))*NB + b)*4);
        f4v accl = {0.f,0.f,0.f,0.f};
        if (s > 0){
          const int slotp = (s-1) % SL;
          const long hb = ((long)slotp*NB + b)*H2 + dir*HID;
          #pragma unroll
          for (int kk = 0; kk < 25; ++kk){
            const int ko = kk*32 + q*8;
            const h8v aw = ldv(p.w1hh + whh_row + ko);
            acc  = __builtin_amdgcn_mfma_f32_16x16x32_f16(aw, ldv(p.h1wh + hb + ko), acc,  0, 0, 0);
            accl = __builtin_amdgcn_mfma_f32_16x16x32_f16(aw, ldv(p.h1wl + hb + ko), accl, 0, 0, 0);
          }
        }
        const float si = 1.f/(1.f + __expf(-(acc[0] + accl[0]*ISC)));
        const float sf = 1.f/(1.f + __expf(-(acc[1] + accl[1]*ISC)));
        const float so = 1.f/(1.f + __expf(-(acc[3] + accl[3]*ISC)));
        cst = sf*cst + si*tanhf(acc[2] + accl[2]*ISC);
        const float h = so*tanhf(cst);
        const _Float16 hi = (_Float16)h;
        hT[0][ulocal][b] = hi;
        hT[1][ulocal][b] = (_Float16)((h - (float)hi)*SCAL);
      }
      __syncthreads();
      if (act && threadIdx.x < 64){
        const int part = threadIdx.x >> 5, bb2 = threadIdx.x & 31;
        const int slot = (ci*Tc + sl) % SL;
        h8v v;
        #pragma unroll
        for (int uu = 0; uu < 8; ++uu) v[uu] = hT[part][uu][bb2];
        _Float16* dst = (part ? p.h1wl : p.h1wh) + ((long)slot*NB + bb2)*H2 + dir*HID + wgd*8;
        *(h8v*)dst = v;
      }
      gbar(p.bar1, ++ep);
    }
    // ---------- logits phase ----------
    for (int pi = blockIdx.x; pi < 2*Tc; pi += gridDim.x){
      const int sl = pi >> 1, d = pi & 1;
      const int s  = ci*Tc + sl;
      const int t  = d ? (LSEQ-1-s) : s;
      const int slot = s % SL;
      const int bb = threadIdx.x & 31;
      const int k0 = threadIdx.x >> 5;
      const _Float16* hp  = p.h1wh + ((long)slot*NB + bb)*H2 + d*HID;
      const _Float16* hp2 = p.h1wl + ((long)slot*NB + bb)*H2 + d*HID;
      float* lp = (d ? p.logits1 : p.logits0) + ((long)t*NB + bb)*20;
      for (int k = k0; k < 20; k += 8){
        const float* wrow = p.w_lin + (long)k*H2 + d*HID;
        float acc2 = 0.f;
        for (int u = 0; u < HID; u += 8){
          h8v hv = ldv(hp + u);
          h8v lv = ldv(hp2 + u);
          #pragma unroll
          for (int j2 = 0; j2 < 8; ++j2)
            acc2 += ((float)hv[j2] + (float)lv[j2]*ISC) * wrow[u + j2];
        }
        lp[k] = acc2;
      }
    }
    gbar(p.bar1, ++ep);
  }
}

// ---- head: logits -> softmax over BATCH axis -> angles -> dvec (reshape-scramble aware)
__global__ void head_kernel(P p){
  const int l = blockIdx.x;
  const int tid = threadIdx.x;
  __shared__ float lg[NB][20];
  __shared__ float sA[20][3], cA2[20][3];
  if (tid < 60){
    const float a = p.alphabet[tid];
    sA[tid/3][tid%3]  = sinf(a);
    cA2[tid/3][tid%3] = cosf(a);
  }
  for (int i = tid; i < NB*20; i += blockDim.x){
    const int bb = i / 20, k = i % 20;
    lg[bb][k] = p.logits0[((long)l*NB + bb)*20 + k] +
                p.logits1[((long)l*NB + bb)*20 + k] + p.b_lin[k];
  }
  __syncthreads();
  if (tid < 20){
    float mx = -1e30f;
    for (int bb=0; bb<NB; ++bb) mx = fmaxf(mx, lg[bb][tid]);
    float sum = 0.f;
    for (int bb=0; bb<NB; ++bb) sum += expf(lg[bb][tid] - mx);
    const float inv = 1.f/sum;
    for (int bb=0; bb<NB; ++bb) lg[bb][tid] = expf(lg[bb][tid] - mx)*inv;
  }
  __syncthreads();
  if (tid < 96){
    const int bb = tid/3, dd = tid%3;     // angle source (ang[l][bb][dd])
    const int pp = tid >> 5;              // scan row within step-triple
    const int j  = tid & 31;              // NeRF lane (column of phis)
    float ss = 0.f, cc = 0.f;
    #pragma unroll
    for (int k=0; k<20; ++k){ ss += lg[bb][k]*sA[k][dd]; cc += lg[bb][k]*cA2[k][dd]; }
    const float phi = atan2f(ss, cc);
    const float BL[3] = {145.801f, 152.326f, 132.868f};
    const float BA[3] = {2.124f, 1.941f, 2.028f};
    const float r = BL[pp], th = BA[pp];
    float* dv = p.dvec + ((long)(l*3 + pp)*NB + j)*4;
    dv[0] = -r*cosf(th);
    dv[1] = r*sinf(th)*cosf(phi);
    dv[2] = r*sinf(th)*sinf(phi);
  }
}

// ---- NeRF extension: strictly sequential, 1 lane per scan column.
__global__ void nerf_kernel(P p){
  const int bb = threadIdx.x;
  if (bb >= NB) return;
  float ax=0.f,ay=0.f,az=0.f, bx=100.f,by=0.f,bz=0.f, cx=200.f,cy=100.f,cz=0.f;
  for (int i = 0; i < 3*LSEQ; ++i){
    const float* dv = p.dvec + ((long)i*NB + bb)*4;
    const float d0=dv[0], d1=dv[1], d2=dv[2];
    float ux=cx-bx, uy=cy-by, uz=cz-bz;
    float inv = 1.f/(sqrtf(ux*ux+uy*uy+uz*uz)+1e-12f);
    ux*=inv; uy*=inv; uz*=inv;
    const float px=bx-ax, py=by-ay, pz=bz-az;
    float nx=py*uz-pz*uy, ny=pz*ux-px*uz, nz=px*uy-py*ux;
    inv = 1.f/(sqrtf(nx*nx+ny*ny+nz*nz)+1e-12f);
    nx*=inv; ny*=inv; nz*=inv;
    const float mx=ny*uz-nz*uy, my=nz*ux-nx*uz, mz=nx*uy-ny*ux;
    const float Dx = cx + d0*ux + d1*mx + d2*nx;
    const float Dy = cy + d0*uy + d1*my + d2*ny;
    const float Dz = cz + d0*uz + d1*mz + d2*nz;
    float* o = p.out + ((long)i*NB + bb)*3;
    o[0]=Dx; o[1]=Dy; o[2]=Dz;
    ax=bx; ay=by; az=bz;
    bx=cx; by=cy; bz=cz;
    cx=Dx; cy=Dy; cz=Dz;
  }
}

extern "C" void kernel_launch(void* const* d_in, const int* in_sizes, int n_in,
                              void* d_out, int out_size, void* d_ws, size_t ws_size,
                              hipStream_t stream){
  P p{};
  p.x      = (const float*)d_in[0];
  p.w_ih0  = (const float*)d_in[1];
  p.w_hh0  = (const float*)d_in[2];
  p.b_ih0  = (const float*)d_in[3];
  p.b_hh0  = (const float*)d_in[4];
  p.w_ih1  = (const float*)d_in[5];
  p.w_hh1  = (const float*)d_in[6];
  p.b_ih1  = (const float*)d_in[7];
  p.b_hh1  = (const float*)d_in[8];
  p.w_lin  = (const float*)d_in[9];
  p.b_lin  = (const float*)d_in[10];
  p.alphabet = (const float*)d_in[11];
  p.out    = (float*)d_out;

  char* base = (char*)d_ws;
  size_t off = 0;
  auto alloc = [&](size_t bytes)->void*{
    void* r = base + off;
    off = (off + bytes + 255) & ~(size_t)255;
    return r;
  };
  p.h0      = (_Float16*)alloc((size_t)LSEQ*NB*H2*2);       // 71.68 MB
  p.hr0h    = (_Float16*)alloc((size_t)2*NB*H2*2);
  p.hr0l    = (_Float16*)alloc((size_t)2*NB*H2*2);
  p.w0hh    = (_Float16*)alloc((size_t)2*G4*HID*2);         // 10.24 MB
  p.w1hh    = (_Float16*)alloc((size_t)2*G4*HID*2);         // 10.24 MB
  p.w1ih    = (_Float16*)alloc((size_t)2*G4*H2*2);          // 20.48 MB
  p.w0ih    = (_Float16*)alloc((size_t)2*G4*DKP*2);
  p.xp      = (_Float16*)alloc((size_t)LSEQ*NB*DKP*2);
  p.bias0   = (float*)alloc((size_t)2*G4*4);
  p.bias1   = (float*)alloc((size_t)2*G4*4);
  p.logits0 = (float*)alloc((size_t)LSEQ*NB*20*4);
  p.logits1 = (float*)alloc((size_t)LSEQ*NB*20*4);
  p.dvec    = (float*)alloc((size_t)3*LSEQ*NB*4*4);
  p.bar0    = (int*)alloc((size_t)BARN*4);
  p.bar1    = (int*)alloc((size_t)BARN*4);

  const int cands[4] = {140, 28, 20, 4};
  int Tc = 4;
  for (int i = 0; i < 4; ++i){
    const size_t need = off
      + (size_t)2*cands[i]*800*NB*4*4 + 256
      + (size_t)2*(cands[i]+1)*NB*H2*2 + 512;
    if (need <= ws_size){ Tc = cands[i]; break; }
  }
  p.gx1  = (float*)alloc((size_t)2*Tc*800*NB*4*4);
  p.h1wh = (_Float16*)alloc((size_t)(Tc+1)*NB*H2*2);
  p.h1wl = (_Float16*)alloc((size_t)(Tc+1)*NB*H2*2);
  p.Tc = Tc;
  p.nchunks = LSEQ / Tc;

  hipLaunchKernelGGL(prep_w, dim3(1024), dim3(256), 0, stream, p.w_hh0, p.w0hh, HID, HID);
  hipLaunchKernelGGL(prep_w, dim3(1024), dim3(256), 0, stream, p.w_hh1, p.w1hh, HID, HID);
  hipLaunchKernelGGL(prep_w, dim3(2048), dim3(256), 0, stream, p.w_ih1, p.w1ih, H2, H2);
  hipLaunchKernelGGL(prep_w, dim3(256),  dim3(256), 0, stream, p.w_ih0, p.w0ih, DIN, DKP);
  hipLaunchKernelGGL(prep_xpad, dim3(512), dim3(256), 0, stream, p.x, p.xp);
  hipLaunchKernelGGL(prep_bias, dim3(32), dim3(256), 0, stream,
                     p.b_ih0, p.b_hh0, p.b_ih1, p.b_hh1, p.bias0, p.bias1, p.bar0, p.bar1);

  void* args[] = { &p };
  hipLaunchCooperativeKernel((void*)layer0_kernel, dim3(256), dim3(256), args, 0, stream);
  hipLaunchCooperativeKernel((void*)layer1_kernel, dim3(256), dim3(256), args, 0, stream);
  hipLaunchKernelGGL(head_kernel, dim3(LSEQ), dim3(256), 0, stream, p);
  hipLaunchKernelGGL(nerf_kernel, dim3(1), dim3(64), 0, stream, p);
}